// Round 8
// baseline (10528.575 us; speedup 1.0000x reference)
//
#include <hip/hip_runtime.h>
#include <hip/hip_bf16.h>

// MEASUREMENT ROUND: kernels wrapped in internal repeat loops (idempotent bodies)
// so each dispatch exceeds the harness's ~320us fill dispatches and appears in the
// rocprof top-5 WITH counters. Also: W repacked to k-panel layout [K/32][1024][32]
// so MFMA B-frag loads are dense 1KB wave accesses (was 16-line gathers).
//   K1: FPS (blocks 0-15) || W->bf16 packed convert (blocks 16-255), x R1 reps
//   K2: fused KNN + gather-fused MFMA GEMM, x R2 reps

#define NPTS 8192
#define SPTS 32
#define KNN_K 12
#define DS 256
#define DT 1024
#define DOUT 1024
#define R1 96
#define R2 48

typedef float f32x4 __attribute__((ext_vector_type(4)));
typedef __bf16 bf16x8 __attribute__((ext_vector_type(8)));
typedef unsigned short ushort_t;
typedef unsigned long long u64;

__device__ __forceinline__ ushort_t f2bf(float f) {
    unsigned int u = __float_as_uint(f);
    u += 0x7fffu + ((u >> 16) & 1u);   // RNE
    return (ushort_t)(u >> 16);
}

// ==================== K1: FPS || W convert (packed) ====================
// Packed layout: element (col,k) -> [k>>5]*(DOUT*32) + col*32 + (k&31)
__global__ __launch_bounds__(512) void fps_convw_kernel(const float* __restrict__ xyz,
                                                        float* __restrict__ new_xyz,
                                                        const float* __restrict__ Wt,
                                                        ushort_t* __restrict__ Wb_t,
                                                        const float* __restrict__ Ws,
                                                        ushort_t* __restrict__ Wb_s) {
    int bid = blockIdx.x;
    int tid = threadIdx.x;

    if (bid >= 16) {
        // W -> bf16 packed (240 blocks)
        int lin = (bid - 16) * 512 + tid;
        const int stride = 240 * 512;
        for (int rep = 0; rep < R1; ++rep) {
            for (int i = lin; i < (DT * DOUT) / 4; i += stride) {   // t: KD=1024
                int col = i >> 8, k4 = i & 255;
                float4 v = reinterpret_cast<const float4*>(Wt)[i];
                ushort4 u;
                u.x = f2bf(v.x); u.y = f2bf(v.y); u.z = f2bf(v.z); u.w = f2bf(v.w);
                size_t off = (size_t)(k4 >> 3) * (DOUT * 32) + col * 32 + (k4 & 7) * 4;
                *reinterpret_cast<ushort4*>(Wb_t + off) = u;
            }
            for (int i = lin; i < (DS * DOUT) / 4; i += stride) {   // s: KD=256
                int col = i >> 6, k4 = i & 63;
                float4 v = reinterpret_cast<const float4*>(Ws)[i];
                ushort4 u;
                u.x = f2bf(v.x); u.y = f2bf(v.y); u.z = f2bf(v.z); u.w = f2bf(v.w);
                size_t off = (size_t)(k4 >> 3) * (DOUT * 32) + col * 32 + (k4 & 7) * 4;
                *reinterpret_cast<ushort4*>(Wb_s + off) = u;
            }
        }
        return;
    }

    // ---- FPS: one block per batch; packed (dist_bits, 8191-idx) u64 argmax ----
    {
#pragma clang fp contract(off)
        int b = bid;
        const float* base = xyz + (size_t)b * NPTS * 3;

        __shared__ float cx[NPTS], cy[NPTS], cz[NPTS];   // 96 KB coord table
        __shared__ u64 rkey[2][8];

        float px[16], py[16], pz[16], dd[16];
#pragma unroll
        for (int i = 0; i < 16; ++i) {
            int p = tid + i * 512;
            px[i] = base[p * 3 + 0];
            py[i] = base[p * 3 + 1];
            pz[i] = base[p * 3 + 2];
            cx[p] = px[i]; cy[p] = py[i]; cz[p] = pz[i];
        }

        int w = tid >> 6;
        for (int rep = 0; rep < R1; ++rep) {
#pragma unroll
            for (int i = 0; i < 16; ++i) dd[i] = 1e10f;

            float lx = base[0], ly = base[1], lz = base[2];
            if (tid == 0) {
                new_xyz[((size_t)b * SPTS + 0) * 3 + 0] = lx;
                new_xyz[((size_t)b * SPTS + 0) * 3 + 1] = ly;
                new_xyz[((size_t)b * SPTS + 0) * 3 + 2] = lz;
            }

            for (int it = 1; it < SPTS; ++it) {
                int par = it & 1;
                u64 bk = 0;
#pragma unroll
                for (int i = 0; i < 16; ++i) {
                    float dx = px[i] - lx, dy = py[i] - ly, dz = pz[i] - lz;
                    float d = dx * dx + dy * dy;
                    d = d + dz * dz;
                    float nd = fminf(dd[i], d);
                    dd[i] = nd;
                    // dist >= 0: float bits order-isomorphic unsigned.
                    // low 32 = 8191-idx: equal dist -> larger low = smaller idx
                    u64 kd = ((u64)__float_as_uint(nd) << 32) | (unsigned)(8191 - (tid + i * 512));
                    bk = (kd > bk) ? kd : bk;
                }
#pragma unroll
                for (int off = 1; off < 64; off <<= 1) {
                    u64 ok = __shfl_xor(bk, off);
                    bk = (ok > bk) ? ok : bk;
                }
                if ((tid & 63) == 0) rkey[par][w] = bk;
                __syncthreads();   // covers cx fill on first pass too
                u64 nk = rkey[par][0];
#pragma unroll
                for (int w2 = 1; w2 < 8; ++w2) {
                    u64 v2 = rkey[par][w2];
                    nk = (v2 > nk) ? v2 : nk;
                }
                int idx = 8191 - (int)(unsigned)(nk & 0xFFFFFFFFull);
                lx = cx[idx]; ly = cy[idx]; lz = cz[idx];   // LDS broadcast
                if (tid == 0) {
                    new_xyz[((size_t)b * SPTS + it) * 3 + 0] = lx;
                    new_xyz[((size_t)b * SPTS + it) * 3 + 1] = ly;
                    new_xyz[((size_t)b * SPTS + it) * 3 + 2] = lz;
                }
            }
            __syncthreads();   // protect rkey across reps
        }
    }
}

// ==================== K2: fused KNN + GEMM ====================

// KNN phase: 4 queries per block, 2 waves per query (4096 pts each).
__device__ __forceinline__ void knn_phase(const float* __restrict__ pts,
                                          const float* __restrict__ new_xyz,
                                          int q0, u64 (*sd)[KNN_K], int (*kidx)[KNN_K]) {
#pragma clang fp contract(off)
    int tid = threadIdx.x;
    int w = tid >> 6, lane = tid & 63;
    int qi = w >> 1, sw = w & 1;
    int q = q0 + qi;

    float qx = new_xyz[q * 3 + 0];
    float qy = new_xyz[q * 3 + 1];
    float qz = new_xyz[q * 3 + 2];
    float qq = qx * qx + qy * qy;
    qq = qq + qz * qz;

    u64 bd[12];
#pragma unroll
    for (int j = 0; j < 12; ++j) bd[j] = ~0ULL;

    for (int i = 0; i < 4096 / 64; ++i) {
        int p = sw * 4096 + i * 64 + lane;
        float p0 = pts[p * 3 + 0], p1 = pts[p * 3 + 1], p2 = pts[p * 3 + 2];
        float pp = p0 * p0 + p1 * p1; pp = pp + p2 * p2;
        float dot = qx * p0 + qy * p1; dot = dot + qz * p2;
        float d = (qq - 2.0f * dot) + pp;  // reference's expanded form
        unsigned u = __float_as_uint(d);
        u = (u & 0x80000000u) ? ~u : (u | 0x80000000u);   // order-isomorphic
        u64 key = ((u64)u << 32) | (unsigned)p;
        if (key < bd[11]) {
#pragma unroll
            for (int j = 11; j > 0; --j) {
                bool keep = (key >= bd[j]);
                u64 sh = (key >= bd[j - 1]) ? key : bd[j - 1];
                bd[j] = keep ? bd[j] : sh;
            }
            if (key < bd[0]) bd[0] = key;
        }
    }

#pragma unroll
    for (int r = 0; r < KNN_K; ++r) {
        u64 cv = bd[0];
#pragma unroll
        for (int off = 1; off < 64; off <<= 1) {
            u64 ov = __shfl_xor(cv, off);
            cv = (ov < cv) ? ov : cv;
        }
        if (lane == 0) sd[w][r] = cv;
        if (cv == bd[0]) {
#pragma unroll
            for (int j = 0; j < 11; ++j) bd[j] = bd[j + 1];
            bd[11] = ~0ULL;
        }
    }
    __syncthreads();

    if (sw == 0) {
        u64 cd = (lane < 24) ? sd[2 * qi + (lane >= 12 ? 1 : 0)][lane >= 12 ? lane - 12 : lane]
                             : ~0ULL;
#pragma unroll
        for (int r = 0; r < KNN_K; ++r) {
            u64 mv = cd;
#pragma unroll
            for (int off = 1; off < 64; off <<= 1) {
                u64 ov = __shfl_xor(mv, off);
                mv = (ov < mv) ? ov : mv;
            }
            if (lane == 0) kidx[qi][r] = (int)(unsigned)(mv & 0xFFFFFFFFull);
            if (cd == mv) cd = ~0ULL;
        }
    }
    __syncthreads();
}

// GEMM: block = 4 queries (64 rows) x 1024 cols; 8 waves of 64x128.
// B from PACKED Wb: frag addr = kk*(DOUT*32) + col*32 + kgrp*8 -> dense 1KB/wave.
template <int KD>
__device__ __forceinline__ void gemm_body(int mblk, const float* __restrict__ feat,
                                          const int (*kidx)[KNN_K],
                                          const ushort_t* __restrict__ Wb,
                                          const float* __restrict__ bias,
                                          const float* __restrict__ gamma,
                                          const float* __restrict__ beta,
                                          const float* __restrict__ mean,
                                          const float* __restrict__ var,
                                          float* __restrict__ out,
                                          ushort_t (*abuf)[64][40]) {
    const int NK = KD / 32;
    int tid = threadIdx.x;
    int w = tid >> 6, lane = tid & 63;
    int lrow = lane & 15, kgrp = lane >> 4;

    // staging role: 8 threads per row, 4 floats each
    int r = tid >> 3, seg = tid & 7;
    int q = mblk * 4 + (r >> 4);
    int k = r & 15;
    bool valid = (k < KNN_K);
    int b = q >> 5;
    int src = valid ? kidx[r >> 4][k] : 0;
    const float* srcp = feat + ((size_t)b * NPTS + src) * KD + seg * 4;

    f32x4 acc[4][8];
#pragma unroll
    for (int mi = 0; mi < 4; ++mi)
#pragma unroll
        for (int ni = 0; ni < 8; ++ni) {
            f32x4 z = {0.f, 0.f, 0.f, 0.f};
            acc[mi][ni] = z;
        }

    // prologue: stage slab 0
    {
        float4 v = {0.f, 0.f, 0.f, 0.f};
        if (valid) v = *reinterpret_cast<const float4*>(srcp);
        ushort4 u;
        u.x = f2bf(v.x); u.y = f2bf(v.y); u.z = f2bf(v.z); u.w = f2bf(v.w);
        *reinterpret_cast<ushort4*>(&abuf[0][r][seg * 4]) = u;
    }
    __syncthreads();

    for (int kk = 0; kk < NK; ++kk) {
        int cur = kk & 1;
        float4 nv = {0.f, 0.f, 0.f, 0.f};
        if (kk + 1 < NK && valid)
            nv = *reinterpret_cast<const float4*>(srcp + (kk + 1) * 32);

        bf16x8 a[4];
#pragma unroll
        for (int mf = 0; mf < 4; ++mf)
            a[mf] = *reinterpret_cast<const bf16x8*>(&abuf[cur][mf * 16 + lrow][kgrp * 8]);

#pragma unroll
        for (int nf = 0; nf < 8; ++nf) {
            int col = w * 128 + nf * 16 + lrow;
            const ushort_t* bp = Wb + (size_t)kk * (DOUT * 32) + (size_t)col * 32 + kgrp * 8;
            bf16x8 bfr = *reinterpret_cast<const bf16x8*>(bp);
#pragma unroll
            for (int mf = 0; mf < 4; ++mf)
                acc[mf][nf] = __builtin_amdgcn_mfma_f32_16x16x32_bf16(a[mf], bfr, acc[mf][nf], 0, 0, 0);
        }

        if (kk + 1 < NK) {
            ushort4 u;
            u.x = f2bf(nv.x); u.y = f2bf(nv.y); u.z = f2bf(nv.z); u.w = f2bf(nv.w);
            *reinterpret_cast<ushort4*>(&abuf[cur ^ 1][r][seg * 4]) = u;
        }
        __syncthreads();
    }

    // epilogue: BN + ReLU + max over rows 0..11
#pragma unroll
    for (int nf = 0; nf < 8; ++nf) {
        int col = w * 128 + nf * 16 + lrow;
        float sc = gamma[col] / sqrtf(var[col] + 1e-5f);
        float sh = (bias[col] - mean[col]) * sc + beta[col];
#pragma unroll
        for (int mf = 0; mf < 4; ++mf) {
            float m;
            if (kgrp < 3) {
                float y0 = fmaxf(acc[mf][nf][0] * sc + sh, 0.0f);
                float y1 = fmaxf(acc[mf][nf][1] * sc + sh, 0.0f);
                float y2 = fmaxf(acc[mf][nf][2] * sc + sh, 0.0f);
                float y3 = fmaxf(acc[mf][nf][3] * sc + sh, 0.0f);
                m = fmaxf(fmaxf(y0, y1), fmaxf(y2, y3));
            } else {
                m = -1e30f;  // pad rows 12..15
            }
            m = fmaxf(m, __shfl_xor(m, 16));
            m = fmaxf(m, __shfl_xor(m, 32));
            if (kgrp == 0) out[(size_t)(mblk * 4 + mf) * DOUT + col] = m;
        }
    }
}

struct GP {
    const float* feature_s; const float* xyz_s;
    const float* feature_t; const float* xyz_t;
    const float* new_xyz;
    const ushort_t* Wb_s; const ushort_t* Wb_t;
    const float* bias_s; const float* gamma_s; const float* beta_s;
    const float* mean_s; const float* var_s;
    const float* bias_t; const float* gamma_t; const float* beta_t;
    const float* mean_t; const float* var_t;
    float* out;
};

__global__ __launch_bounds__(512, 2) void knn_gemm_kernel(GP P) {
    __shared__ ushort_t abuf[2][64][40];
    __shared__ u64 sd[8][KNN_K];
    __shared__ int kidx[4][KNN_K];

    int bid = blockIdx.x;
    bool is_t = (bid < 128);
    int mblk = is_t ? bid : bid - 128;
    int q0 = mblk * 4;
    int b = q0 >> 5;

    const float* pts = (is_t ? P.xyz_t : P.xyz_s) + (size_t)b * NPTS * 3;

    for (int rep = 0; rep < R2; ++rep) {
        knn_phase(pts, P.new_xyz, q0, sd, kidx);
        if (is_t) {
            gemm_body<DT>(mblk, P.feature_t, kidx, P.Wb_t, P.bias_t, P.gamma_t, P.beta_t,
                          P.mean_t, P.var_t, P.out + (size_t)512 * 1024, abuf);
        } else {
            gemm_body<DS>(mblk, P.feature_s, kidx, P.Wb_s, P.bias_s, P.gamma_s, P.beta_s,
                          P.mean_s, P.var_s, P.out, abuf);
        }
        __syncthreads();   // protect LDS reuse across reps
    }
}

extern "C" void kernel_launch(void* const* d_in, const int* in_sizes, int n_in,
                              void* d_out, int out_size, void* d_ws, size_t ws_size,
                              hipStream_t stream) {
    const float* feature_s = (const float*)d_in[0];
    const float* xyz_s     = (const float*)d_in[1];
    const float* feature_t = (const float*)d_in[2];
    const float* xyz_t     = (const float*)d_in[3];
    const float* Ws        = (const float*)d_in[4];
    const float* Wt        = (const float*)d_in[10];
    float* out = (float*)d_out;

    char* ws = (char*)d_ws;
    float* new_xyz  = (float*)(ws + 0);
    ushort_t* Wb_s  = (ushort_t*)(ws + 57344);
    ushort_t* Wb_t  = (ushort_t*)(ws + 581632);

    fps_convw_kernel<<<256, 512, 0, stream>>>(xyz_t, new_xyz, Wt, Wb_t, Ws, Wb_s);

    GP P;
    P.feature_s = feature_s; P.xyz_s = xyz_s;
    P.feature_t = feature_t; P.xyz_t = xyz_t;
    P.new_xyz = new_xyz;
    P.Wb_s = Wb_s; P.Wb_t = Wb_t;
    P.bias_s = (const float*)d_in[5];  P.gamma_s = (const float*)d_in[6];
    P.beta_s = (const float*)d_in[7];  P.mean_s  = (const float*)d_in[8];
    P.var_s  = (const float*)d_in[9];
    P.bias_t = (const float*)d_in[11]; P.gamma_t = (const float*)d_in[12];
    P.beta_t = (const float*)d_in[13]; P.mean_t  = (const float*)d_in[14];
    P.var_t  = (const float*)d_in[15];
    P.out = out;

    knn_gemm_kernel<<<256, 512, 0, stream>>>(P);
}

// Round 9
// 108.578 us; speedup vs baseline: 96.9679x; 96.9679x over previous
//
#include <hip/hip_runtime.h>
#include <hip/hip_bf16.h>

// RelationCos pipeline in 3 kernels (occupancy-first restructure):
//   K1: FPS (blocks 0-15, packed-u64 argmax + LDS coord table) || W->bf16 packed (16-255)
//   K2: KNN (512 blocks = 1/query; 4 waves per set x 2048 pts; packed-u64) -> idx in ws
//   K3: gather-fused MFMA GEMM, 512 uniform blocks (4 queries x 512 cols, 2 blocks/CU)
// W packed to k-panels [K/32][1024][32] so B-frag loads are dense 1KB wave accesses.

#define NPTS 8192
#define SPTS 32
#define KNN_K 12
#define DS 256
#define DT 1024
#define DOUT 1024

typedef float f32x4 __attribute__((ext_vector_type(4)));
typedef __bf16 bf16x8 __attribute__((ext_vector_type(8)));
typedef unsigned short ushort_t;
typedef unsigned long long u64;

__device__ __forceinline__ ushort_t f2bf(float f) {
    unsigned int u = __float_as_uint(f);
    u += 0x7fffu + ((u >> 16) & 1u);   // RNE
    return (ushort_t)(u >> 16);
}

// ==================== K1: FPS || W convert (packed) ====================
// Packed layout: element (col,k) -> [k>>5]*(DOUT*32) + col*32 + (k&31)
__global__ __launch_bounds__(512) void fps_convw_kernel(const float* __restrict__ xyz,
                                                        float* __restrict__ new_xyz,
                                                        const float* __restrict__ Wt,
                                                        ushort_t* __restrict__ Wb_t,
                                                        const float* __restrict__ Ws,
                                                        ushort_t* __restrict__ Wb_s) {
    int bid = blockIdx.x;
    int tid = threadIdx.x;

    if (bid >= 16) {
        // W -> bf16 packed (240 blocks)
        int lin = (bid - 16) * 512 + tid;
        const int stride = 240 * 512;
        for (int i = lin; i < (DT * DOUT) / 4; i += stride) {   // t: KD=1024
            int col = i >> 8, k4 = i & 255;
            float4 v = reinterpret_cast<const float4*>(Wt)[i];
            ushort4 u;
            u.x = f2bf(v.x); u.y = f2bf(v.y); u.z = f2bf(v.z); u.w = f2bf(v.w);
            size_t off = (size_t)(k4 >> 3) * (DOUT * 32) + col * 32 + (k4 & 7) * 4;
            *reinterpret_cast<ushort4*>(Wb_t + off) = u;
        }
        for (int i = lin; i < (DS * DOUT) / 4; i += stride) {   // s: KD=256
            int col = i >> 6, k4 = i & 63;
            float4 v = reinterpret_cast<const float4*>(Ws)[i];
            ushort4 u;
            u.x = f2bf(v.x); u.y = f2bf(v.y); u.z = f2bf(v.z); u.w = f2bf(v.w);
            size_t off = (size_t)(k4 >> 3) * (DOUT * 32) + col * 32 + (k4 & 7) * 4;
            *reinterpret_cast<ushort4*>(Wb_s + off) = u;
        }
        return;
    }

    // ---- FPS: one block per batch; packed (dist_bits, 8191-idx) u64 argmax ----
    {
#pragma clang fp contract(off)
        int b = bid;
        const float* base = xyz + (size_t)b * NPTS * 3;

        __shared__ float cx[NPTS], cy[NPTS], cz[NPTS];   // 96 KB coord table
        __shared__ u64 rkey[2][8];

        float px[16], py[16], pz[16], dd[16];
#pragma unroll
        for (int i = 0; i < 16; ++i) {
            int p = tid + i * 512;
            px[i] = base[p * 3 + 0];
            py[i] = base[p * 3 + 1];
            pz[i] = base[p * 3 + 2];
            dd[i] = 1e10f;
            cx[p] = px[i]; cy[p] = py[i]; cz[p] = pz[i];
        }

        float lx = base[0], ly = base[1], lz = base[2];
        if (tid == 0) {
            new_xyz[((size_t)b * SPTS + 0) * 3 + 0] = lx;
            new_xyz[((size_t)b * SPTS + 0) * 3 + 1] = ly;
            new_xyz[((size_t)b * SPTS + 0) * 3 + 2] = lz;
        }

        int w = tid >> 6;
        for (int it = 1; it < SPTS; ++it) {
            int par = it & 1;
            u64 bk = 0;
#pragma unroll
            for (int i = 0; i < 16; ++i) {
                float dx = px[i] - lx, dy = py[i] - ly, dz = pz[i] - lz;
                float d = dx * dx + dy * dy;
                d = d + dz * dz;
                float nd = fminf(dd[i], d);
                dd[i] = nd;
                // dist >= 0: float bits order-isomorphic unsigned.
                // low 32 = 8191-idx: equal dist -> larger low = smaller idx (first occurrence)
                u64 kd = ((u64)__float_as_uint(nd) << 32) | (unsigned)(8191 - (tid + i * 512));
                bk = (kd > bk) ? kd : bk;
            }
#pragma unroll
            for (int off = 1; off < 64; off <<= 1) {
                u64 ok = __shfl_xor(bk, off);
                bk = (ok > bk) ? ok : bk;
            }
            if ((tid & 63) == 0) rkey[par][w] = bk;
            __syncthreads();   // one barrier/iter (parity dbuf); also covers cx fill
            u64 nk = rkey[par][0];
#pragma unroll
            for (int w2 = 1; w2 < 8; ++w2) {
                u64 v2 = rkey[par][w2];
                nk = (v2 > nk) ? v2 : nk;
            }
            int idx = 8191 - (int)(unsigned)(nk & 0xFFFFFFFFull);
            lx = cx[idx]; ly = cy[idx]; lz = cz[idx];   // LDS broadcast
            if (tid == 0) {
                new_xyz[((size_t)b * SPTS + it) * 3 + 0] = lx;
                new_xyz[((size_t)b * SPTS + it) * 3 + 1] = ly;
                new_xyz[((size_t)b * SPTS + it) * 3 + 2] = lz;
            }
        }
    }
}

// ==================== K2: KNN ====================
// 512 blocks (one per query) x 8 waves: waves 0-3 set s, 4-7 set t; 2048 pts/wave
// (32 serial iters). Packed key = (monotone(bits(d))<<32)|idx; per-wave 12-pop ->
// LDS; waves 0/4 merge 48 candidates -> global idx. 2 blocks/CU.
__global__ __launch_bounds__(512) void knn_kernel(const float* __restrict__ xyz_s,
                                                  const float* __restrict__ xyz_t,
                                                  const float* __restrict__ new_xyz,
                                                  int* __restrict__ idx_s,
                                                  int* __restrict__ idx_t) {
#pragma clang fp contract(off)
    int q = blockIdx.x;
    int tid = threadIdx.x;
    int w = tid >> 6, lane = tid & 63;
    int set = w >> 2;        // 0 = s, 1 = t
    int sw = w & 3;          // wave within set
    int b = q >> 5;

    const float* pts = (set ? xyz_t : xyz_s) + (size_t)b * NPTS * 3;

    float qx = new_xyz[q * 3 + 0];
    float qy = new_xyz[q * 3 + 1];
    float qz = new_xyz[q * 3 + 2];
    float qq = qx * qx + qy * qy;
    qq = qq + qz * qz;

    u64 bd[12];
#pragma unroll
    for (int j = 0; j < 12; ++j) bd[j] = ~0ULL;

    for (int i = 0; i < 2048 / 64; ++i) {
        int p = sw * 2048 + i * 64 + lane;
        float p0 = pts[p * 3 + 0], p1 = pts[p * 3 + 1], p2 = pts[p * 3 + 2];
        float pp = p0 * p0 + p1 * p1; pp = pp + p2 * p2;
        float dot = qx * p0 + qy * p1; dot = dot + qz * p2;
        float d = (qq - 2.0f * dot) + pp;  // reference's expanded form
        unsigned u = __float_as_uint(d);
        u = (u & 0x80000000u) ? ~u : (u | 0x80000000u);   // order-isomorphic
        u64 key = ((u64)u << 32) | (unsigned)p;
        if (key < bd[11]) {
#pragma unroll
            for (int j = 11; j > 0; --j) {
                bool keep = (key >= bd[j]);
                u64 sh = (key >= bd[j - 1]) ? key : bd[j - 1];
                bd[j] = keep ? bd[j] : sh;
            }
            if (key < bd[0]) bd[0] = key;
        }
    }

    __shared__ u64 sd[2][48];

#pragma unroll
    for (int r = 0; r < KNN_K; ++r) {
        u64 cv = bd[0];
#pragma unroll
        for (int off = 1; off < 64; off <<= 1) {
            u64 ov = __shfl_xor(cv, off);
            cv = (ov < cv) ? ov : cv;
        }
        if (lane == 0) sd[set][sw * KNN_K + r] = cv;
        if (cv == bd[0]) {   // winner lane pops sorted head; keys unique
#pragma unroll
            for (int j = 0; j < 11; ++j) bd[j] = bd[j + 1];
            bd[11] = ~0ULL;
        }
    }
    __syncthreads();

    if (sw == 0) {
        int* outp = (set ? idx_t : idx_s) + q * KNN_K;
        u64 cd = (lane < 48) ? sd[set][lane] : ~0ULL;
#pragma unroll
        for (int r = 0; r < KNN_K; ++r) {
            u64 mv = cd;
#pragma unroll
            for (int off = 1; off < 64; off <<= 1) {
                u64 ov = __shfl_xor(mv, off);
                mv = (ov < mv) ? ov : mv;
            }
            if (lane == 0) outp[r] = (int)(unsigned)(mv & 0xFFFFFFFFull);
            if (cd == mv) cd = ~0ULL;
        }
    }
}

// ==================== K3: gather-fused GEMM ====================
// 512 uniform blocks: (set, query-group, col-half). Block = 4 queries (64 rows,
// 12 valid/query) x 512 cols; 8 waves of 64x64 (acc 4x4). Per K-step stage
// 64x32 f32 -> bf16 LDS (dbuf, [64][40] pad); B dense from packed Wb.
// C/D frag: col=lane&15, row=(lane>>4)*4+reg.
template <int KD>
__device__ __forceinline__ void gemm_body(int mblk, int ch, const float* __restrict__ feat,
                                          const int* __restrict__ idx,
                                          const ushort_t* __restrict__ Wb,
                                          const float* __restrict__ bias,
                                          const float* __restrict__ gamma,
                                          const float* __restrict__ beta,
                                          const float* __restrict__ mean,
                                          const float* __restrict__ var,
                                          float* __restrict__ out,
                                          ushort_t (*abuf)[64][40]) {
    const int NK = KD / 32;
    int tid = threadIdx.x;
    int w = tid >> 6, lane = tid & 63;
    int lrow = lane & 15, kgrp = lane >> 4;

    // staging role: 8 threads per row, 4 floats each
    int r = tid >> 3, seg = tid & 7;
    int q = mblk * 4 + (r >> 4);
    int k = r & 15;
    bool valid = (k < KNN_K);
    int b = q >> 5;
    int src = valid ? idx[q * KNN_K + k] : 0;
    const float* srcp = feat + ((size_t)b * NPTS + src) * KD + seg * 4;

    f32x4 acc[4][4];
#pragma unroll
    for (int mi = 0; mi < 4; ++mi)
#pragma unroll
        for (int ni = 0; ni < 4; ++ni) {
            f32x4 z = {0.f, 0.f, 0.f, 0.f};
            acc[mi][ni] = z;
        }

    // prologue: stage slab 0
    {
        float4 v = {0.f, 0.f, 0.f, 0.f};
        if (valid) v = *reinterpret_cast<const float4*>(srcp);
        ushort4 u;
        u.x = f2bf(v.x); u.y = f2bf(v.y); u.z = f2bf(v.z); u.w = f2bf(v.w);
        *reinterpret_cast<ushort4*>(&abuf[0][r][seg * 4]) = u;
    }
    __syncthreads();

    for (int kk = 0; kk < NK; ++kk) {
        int cur = kk & 1;
        float4 nv = {0.f, 0.f, 0.f, 0.f};
        if (kk + 1 < NK && valid)
            nv = *reinterpret_cast<const float4*>(srcp + (kk + 1) * 32);

        bf16x8 a[4];
#pragma unroll
        for (int mf = 0; mf < 4; ++mf)
            a[mf] = *reinterpret_cast<const bf16x8*>(&abuf[cur][mf * 16 + lrow][kgrp * 8]);

#pragma unroll
        for (int nf = 0; nf < 4; ++nf) {
            int col = ch * 512 + w * 64 + nf * 16 + lrow;
            const ushort_t* bp = Wb + (size_t)kk * (DOUT * 32) + (size_t)col * 32 + kgrp * 8;
            bf16x8 bfr = *reinterpret_cast<const bf16x8*>(bp);
#pragma unroll
            for (int mf = 0; mf < 4; ++mf)
                acc[mf][nf] = __builtin_amdgcn_mfma_f32_16x16x32_bf16(a[mf], bfr, acc[mf][nf], 0, 0, 0);
        }

        if (kk + 1 < NK) {
            ushort4 u;
            u.x = f2bf(nv.x); u.y = f2bf(nv.y); u.z = f2bf(nv.z); u.w = f2bf(nv.w);
            *reinterpret_cast<ushort4*>(&abuf[cur ^ 1][r][seg * 4]) = u;
        }
        __syncthreads();
    }

    // epilogue: BN + ReLU + max over rows 0..11
#pragma unroll
    for (int nf = 0; nf < 4; ++nf) {
        int col = ch * 512 + w * 64 + nf * 16 + lrow;
        float sc = gamma[col] / sqrtf(var[col] + 1e-5f);
        float sh = (bias[col] - mean[col]) * sc + beta[col];
#pragma unroll
        for (int mf = 0; mf < 4; ++mf) {
            float m;
            if (kgrp < 3) {
                float y0 = fmaxf(acc[mf][nf][0] * sc + sh, 0.0f);
                float y1 = fmaxf(acc[mf][nf][1] * sc + sh, 0.0f);
                float y2 = fmaxf(acc[mf][nf][2] * sc + sh, 0.0f);
                float y3 = fmaxf(acc[mf][nf][3] * sc + sh, 0.0f);
                m = fmaxf(fmaxf(y0, y1), fmaxf(y2, y3));
            } else {
                m = -1e30f;  // pad rows 12..15
            }
            m = fmaxf(m, __shfl_xor(m, 16));
            m = fmaxf(m, __shfl_xor(m, 32));
            if (kgrp == 0) out[(size_t)(mblk * 4 + mf) * DOUT + col] = m;
        }
    }
}

struct GP {
    const float* feature_s; const float* feature_t;
    const int* idx_s; const int* idx_t;
    const ushort_t* Wb_s; const ushort_t* Wb_t;
    const float* bias_s; const float* gamma_s; const float* beta_s;
    const float* mean_s; const float* var_s;
    const float* bias_t; const float* gamma_t; const float* beta_t;
    const float* mean_t; const float* var_t;
    float* out;
};

__global__ __launch_bounds__(512, 4) void gemm_kernel(GP P) {
    __shared__ ushort_t abuf[2][64][40];
    int bid = blockIdx.x;
    bool is_t = (bid < 256);           // t first: long poles start earliest
    int r2 = bid & 255;
    int mblk = r2 >> 1, ch = r2 & 1;
    if (is_t) {
        gemm_body<DT>(mblk, ch, P.feature_t, P.idx_t, P.Wb_t, P.bias_t, P.gamma_t,
                      P.beta_t, P.mean_t, P.var_t, P.out + (size_t)512 * 1024, abuf);
    } else {
        gemm_body<DS>(mblk, ch, P.feature_s, P.idx_s, P.Wb_s, P.bias_s, P.gamma_s,
                      P.beta_s, P.mean_s, P.var_s, P.out, abuf);
    }
}

extern "C" void kernel_launch(void* const* d_in, const int* in_sizes, int n_in,
                              void* d_out, int out_size, void* d_ws, size_t ws_size,
                              hipStream_t stream) {
    const float* feature_s = (const float*)d_in[0];
    const float* xyz_s     = (const float*)d_in[1];
    const float* feature_t = (const float*)d_in[2];
    const float* xyz_t     = (const float*)d_in[3];
    const float* Ws        = (const float*)d_in[4];
    const float* Wt        = (const float*)d_in[10];
    float* out = (float*)d_out;

    char* ws = (char*)d_ws;
    float* new_xyz  = (float*)(ws + 0);
    int* idx_s      = (int*)(ws + 8192);
    int* idx_t      = (int*)(ws + 32768);
    ushort_t* Wb_s  = (ushort_t*)(ws + 57344);
    ushort_t* Wb_t  = (ushort_t*)(ws + 581632);

    fps_convw_kernel<<<256, 512, 0, stream>>>(xyz_t, new_xyz, Wt, Wb_t, Ws, Wb_s);
    knn_kernel<<<512, 512, 0, stream>>>(xyz_s, xyz_t, new_xyz, idx_s, idx_t);

    GP P;
    P.feature_s = feature_s; P.feature_t = feature_t;
    P.idx_s = idx_s; P.idx_t = idx_t;
    P.Wb_s = Wb_s; P.Wb_t = Wb_t;
    P.bias_s = (const float*)d_in[5];  P.gamma_s = (const float*)d_in[6];
    P.beta_s = (const float*)d_in[7];  P.mean_s  = (const float*)d_in[8];
    P.var_s  = (const float*)d_in[9];
    P.bias_t = (const float*)d_in[11]; P.gamma_t = (const float*)d_in[12];
    P.beta_t = (const float*)d_in[13]; P.mean_t  = (const float*)d_in[14];
    P.var_t  = (const float*)d_in[15];
    P.out = out;

    gemm_kernel<<<512, 512, 0, stream>>>(P);
}